// Round 1
// baseline (1848.772 us; speedup 1.0000x reference)
//
#include <hip/hip_runtime.h>

#define C 32

// ---------------- kernel 1: scatter avg-pool accumulate (raw sums) ----------
// thread t -> pair p = t>>3, channel-quad c4 = t&7. 4 scalar atomics per thread.
__global__ __launch_bounds__(256) void k_pool(const float* __restrict__ feat,
                                              const int* __restrict__ pin,
                                              const int* __restrict__ pout,
                                              float* __restrict__ pooled, int P) {
  long t = (long)blockIdx.x * blockDim.x + threadIdx.x;
  int p = (int)(t >> 3);
  if (p >= P) return;
  int c4 = (int)(t & 7);
  int i = pin[p], o = pout[p];
  const float4 v = *(const float4*)(feat + (long)i * C + c4 * 4);
  float* dst = pooled + (long)o * C + c4 * 4;
  atomicAdd(dst + 0, v.x);
  atomicAdd(dst + 1, v.y);
  atomicAdd(dst + 2, v.z);
  atomicAdd(dst + 3, v.w);
}

// ---------------- kernel 2: out = feat - bias (streaming init) --------------
__global__ __launch_bounds__(256) void k_init(const float* __restrict__ feat,
                                              const float* __restrict__ bias,
                                              float* __restrict__ out, long total) {
  long idx = (long)blockIdx.x * blockDim.x + threadIdx.x; // float4 index
  if (idx * 4 >= total) return;
  int c4 = (int)(idx & 7); // 8 float4 per 32-channel row
  float4 f = *(const float4*)(feat + idx * 4);
  float4 b = *(const float4*)(bias + c4 * 4);
  float4 r;
  r.x = f.x - b.x; r.y = f.y - b.y; r.z = f.z - b.z; r.w = f.w - b.w;
  *(float4*)(out + idx * 4) = r;
}

// ---------------- kernel 3: transposed-conv scatter -------------------------
// 32 lanes per pair (lane = out-channel d). W column cached in 32 VGPRs,
// reloaded only when k changes (up_k is sorted, so reloads are rare).
// acc = sum_c pooled_rawsum[in][c] * W[k][c][d];  out[o][d] -= acc / counts[in]
__global__ __launch_bounds__(256) void k_conv(const float* __restrict__ pooled,
                                              const int* __restrict__ counts,
                                              const float* __restrict__ W,
                                              const int* __restrict__ uin,
                                              const int* __restrict__ uout,
                                              const int* __restrict__ uk,
                                              float* __restrict__ out, int Q,
                                              int pairs_per_block) {
  int d = threadIdx.x & 31;
  int g = threadIdx.x >> 5;       // pair-group within block
  int ngroups = blockDim.x >> 5;  // 8 for 256 threads
  int q0 = blockIdx.x * pairs_per_block;
  int qend = q0 + pairs_per_block;
  if (qend > Q) qend = Q;

  float wcol[C];
  int kcur = -1;
  for (int q = q0 + g; q < qend; q += ngroups) {
    int in = uin[q];
    int o = uout[q];
    int k = uk[q];
    if (k != kcur) {
      kcur = k;
      const float* wp = W + (long)k * C * C + d;
#pragma unroll
      for (int c = 0; c < C; ++c) wcol[c] = wp[c * C];
    }
    float rc = 1.0f / (float)counts[in];
    const float4* pv = (const float4*)(pooled + (long)in * C);
    float acc = 0.f;
#pragma unroll
    for (int c4 = 0; c4 < 8; ++c4) {
      float4 v = pv[c4];
      acc += v.x * wcol[c4 * 4 + 0];
      acc += v.y * wcol[c4 * 4 + 1];
      acc += v.z * wcol[c4 * 4 + 2];
      acc += v.w * wcol[c4 * 4 + 3];
    }
    atomicAdd(out + (long)o * C + d, -acc * rc);
  }
}

extern "C" void kernel_launch(void* const* d_in, const int* in_sizes, int n_in,
                              void* d_out, int out_size, void* d_ws, size_t ws_size,
                              hipStream_t stream) {
  const float* feat  = (const float*)d_in[0];
  const float* W     = (const float*)d_in[1];
  const float* bias  = (const float*)d_in[2];
  const int* pin     = (const int*)d_in[3];
  const int* pout    = (const int*)d_in[4];
  const int* counts  = (const int*)d_in[5];
  const int* uin     = (const int*)d_in[6];
  const int* uout    = (const int*)d_in[7];
  const int* uk      = (const int*)d_in[8];
  float* out = (float*)d_out;

  const int P = in_sizes[3];
  const int M = in_sizes[5];
  const int Q = in_sizes[6];
  const long NC = (long)in_sizes[0];

  float* pooled = (float*)d_ws;

  // zero the pooled accumulator (ws is poisoned 0xAA each iteration)
  hipMemsetAsync(pooled, 0, (size_t)M * C * sizeof(float), stream);

  { // pool scatter
    long T = (long)P * 8;
    int blocks = (int)((T + 255) / 256);
    k_pool<<<blocks, 256, 0, stream>>>(feat, pin, pout, pooled, P);
  }
  { // out = feat - bias
    long T4 = NC / 4;
    int blocks = (int)((T4 + 255) / 256);
    k_init<<<blocks, 256, 0, stream>>>(feat, bias, out, NC);
  }
  { // transposed conv scatter
    const int PPB = 64; // pairs per block (256 threads = 8 groups x 8 iters)
    int blocks = (Q + PPB - 1) / PPB;
    k_conv<<<blocks, 256, 0, stream>>>(pooled, counts, W, uin, uout, uk, out, Q, PPB);
  }
}